// Round 2
// baseline (793.532 us; speedup 1.0000x reference)
//
#include <hip/hip_runtime.h>
#include <hip/hip_bf16.h>

typedef float f32x4 __attribute__((ext_vector_type(4)));
typedef short short8 __attribute__((ext_vector_type(8)));
typedef unsigned short u16x4 __attribute__((ext_vector_type(4)));

#define N_B 16
#define L_DIM 2048
#define S_DIM 2048
#define D_DIM 128
#define PPAD 16
#define PSTRIDE (S_DIM + PPAD)

static __device__ __forceinline__ unsigned short f2bf(float f) {
  unsigned int u = __builtin_bit_cast(unsigned int, f);
  u = u + 0x7fffu + ((u >> 16) & 1u);
  return (unsigned short)(u >> 16);
}
static __device__ __forceinline__ float bf2f(unsigned short h) {
  unsigned int u = ((unsigned int)h) << 16;
  return __builtin_bit_cast(float, u);
}

// ---------- pre-kernel 0: detect mask element width ----------
// If bools are byte-packed, a random int32 view has words >1 w.p. ~0.66 each.
// If the mask is int32 0/1, every word is 0 or 1.  flag=1 -> byte mask.
__global__ void detect_mask_kernel(const unsigned int* __restrict__ m, int* __restrict__ flag) {
  __shared__ unsigned int red[256];
  unsigned int v = 0;
  for (int i = threadIdx.x; i < 16384; i += 256) v |= m[i];
  red[threadIdx.x] = v;
  __syncthreads();
  if (threadIdx.x == 0) {
    unsigned int o = 0;
#pragma unroll
    for (int i = 0; i < 256; ++i) o |= red[i];
    *flag = (o > 1u) ? 1 : 0;
  }
}

// ---------- pre-kernel 1: K fp32 -> bf16 (same [n][s][d] layout) ----------
__global__ void cvt_k_kernel(const float* __restrict__ K, unsigned short* __restrict__ Kb) {
  const int total4 = N_B * S_DIM * D_DIM / 4;
  for (int i = blockIdx.x * blockDim.x + threadIdx.x; i < total4; i += gridDim.x * blockDim.x) {
    f32x4 f = ((const f32x4*)K)[i];
    u16x4 o = { f2bf(f[0]), f2bf(f[1]), f2bf(f[2]), f2bf(f[3]) };
    ((u16x4*)Kb)[i] = o;
  }
}

// ---------- pre-kernel 2: V fp32 [n][s][d] -> bf16 V^T [n][d][s] ----------
__global__ void transpose_v_kernel(const float* __restrict__ V, unsigned short* __restrict__ Vt) {
  __shared__ unsigned short tile[64][72];
  const int n = blockIdx.z;
  const int s0 = blockIdx.x * 64;
  const int d0 = blockIdx.y * 64;
  const int t = threadIdx.x;
  const int tr = t >> 4;
  const int tc = (t & 15) << 2;
  const float* src = V + (((size_t)n * S_DIM) + s0) * D_DIM + d0;
#pragma unroll
  for (int rr = 0; rr < 64; rr += 16) {
    f32x4 f = *(const f32x4*)(src + (size_t)(tr + rr) * D_DIM + tc);
    tile[tr + rr][tc + 0] = f2bf(f[0]);
    tile[tr + rr][tc + 1] = f2bf(f[1]);
    tile[tr + rr][tc + 2] = f2bf(f[2]);
    tile[tr + rr][tc + 3] = f2bf(f[3]);
  }
  __syncthreads();
  unsigned short* dst = Vt + (((size_t)n * D_DIM) + d0) * (size_t)S_DIM + s0;
#pragma unroll
  for (int rr = 0; rr < 64; rr += 16) {
    const int dr = tr + rr;
    u16x4 o = { tile[tc + 0][dr], tile[tc + 1][dr], tile[tc + 2][dr], tile[tc + 3][dr] };
    *(u16x4*)(dst + (size_t)dr * S_DIM + tc) = o;
  }
}

// ---------- main fused attention kernel ----------
// block: 256 threads (4 waves), handles one n and 16 L-rows.
// wave w covers S-columns [s0 + w*64, s0 + w*64 + 64) per 256-wide chunk.
__global__ __launch_bounds__(256, 2) void attn_main(
    const float* __restrict__ Q, const void* __restrict__ mask_raw,
    const int* __restrict__ flagp,
    const unsigned short* __restrict__ Kb, const unsigned short* __restrict__ Vt,
    float* __restrict__ out_x, float* __restrict__ out_w) {
  __shared__ unsigned short Pl[16 * PSTRIDE];   // 66,048 B: unnormalized exp(l) tile, bf16
  __shared__ float xbuf[16 * D_DIM];            // 8 KB: PV partial reduction
  __shared__ float zrow[16];                    // row sums -> inv

  const int n = blockIdx.y;
  const int l0 = blockIdx.x * 16;
  const int tid = threadIdx.x;
  const int w = tid >> 6;
  const int lane = tid & 63;
  const int g = lane >> 4;
  const int lm = lane & 15;

  const int mask_is_byte = flagp ? *flagp : 0;
  const unsigned char* maskb = (const unsigned char*)mask_raw;
  const int* maski = (const int*)mask_raw;

  for (int i = tid; i < 16 * D_DIM; i += 256) xbuf[i] = 0.0f;
  if (tid < 16) zrow[tid] = 0.0f;
  __syncthreads();

  // Q fragments (A operand, 4 k-steps of 32 over D=128): lane holds row lm, k = ks*32 + g*8 + j
  short8 aq[4];
  {
    const float* qp = Q + (((size_t)n * L_DIM) + l0 + lm) * D_DIM + g * 8;
#pragma unroll
    for (int ks = 0; ks < 4; ++ks) {
      f32x4 f0 = *(const f32x4*)(qp + ks * 32);
      f32x4 f1 = *(const f32x4*)(qp + ks * 32 + 4);
      short8 a;
      a[0] = (short)f2bf(f0[0]); a[1] = (short)f2bf(f0[1]);
      a[2] = (short)f2bf(f0[2]); a[3] = (short)f2bf(f0[3]);
      a[4] = (short)f2bf(f1[0]); a[5] = (short)f2bf(f1[1]);
      a[6] = (short)f2bf(f1[2]); a[7] = (short)f2bf(f1[3]);
      aq[ks] = a;
    }
  }

  f32x4 accx[8];
#pragma unroll
  for (int dt = 0; dt < 8; ++dt) accx[dt] = (f32x4){0.f, 0.f, 0.f, 0.f};
  float rsum[4] = {0.f, 0.f, 0.f, 0.f};

  const float SCL = 0.08838834764831845f * 1.4426950408889634f;  // 1/sqrt(128) * log2(e)

  for (int s0 = 0; s0 < S_DIM; s0 += 256) {
    const int c0 = s0 + w * 64;

    // ---- QK^T: 4 col-tiles of 16, K=128 in 4 MFMA k-steps ----
    f32x4 accqk[4];
#pragma unroll
    for (int nt = 0; nt < 4; ++nt) {
      f32x4 acc = (f32x4){0.f, 0.f, 0.f, 0.f};
      const unsigned short* kp = Kb + (((size_t)n * S_DIM) + c0 + nt * 16 + lm) * D_DIM + g * 8;
#pragma unroll
      for (int ks = 0; ks < 4; ++ks) {
        short8 bk = *(const short8*)(kp + ks * 32);
        acc = __builtin_amdgcn_mfma_f32_16x16x32_bf16(aq[ks], bk, acc, 0, 0, 0);
      }
      accqk[nt] = acc;
    }

    // ---- mask + exp + stash bf16 P in LDS + row-sum ----
    // C layout: lane holds col = c0+nt*16+lm, rows = 4g+r
#pragma unroll
    for (int nt = 0; nt < 4; ++nt) {
      const int col = c0 + nt * 16 + lm;
      const size_t base = (((size_t)n * L_DIM) + l0 + 4 * g) * (size_t)S_DIM + col;
      unsigned int mb[4];
      if (mask_is_byte) {
#pragma unroll
        for (int r = 0; r < 4; ++r)
          mb[r] = __builtin_nontemporal_load(maskb + base + (size_t)r * S_DIM);
      } else {
#pragma unroll
        for (int r = 0; r < 4; ++r)
          mb[r] = (unsigned int)__builtin_nontemporal_load(maski + base + (size_t)r * S_DIM);
      }
#pragma unroll
      for (int r = 0; r < 4; ++r) {
        float p = mb[r] ? 0.0f : exp2f(accqk[nt][r] * SCL);
        rsum[r] += p;
        Pl[(4 * g + r) * PSTRIDE + col] = f2bf(p);
      }
    }

    // ---- PV: A = P (from LDS, same wave's cols — no barrier needed), B = V^T frags ----
    short8 pa[2];
#pragma unroll
    for (int kk = 0; kk < 2; ++kk)
      pa[kk] = *(const short8*)&Pl[lm * PSTRIDE + c0 + kk * 32 + g * 8];
#pragma unroll
    for (int dt = 0; dt < 8; ++dt) {
      const unsigned short* vp = Vt + (((size_t)n * D_DIM) + dt * 16 + lm) * (size_t)S_DIM + c0 + g * 8;
      accx[dt] = __builtin_amdgcn_mfma_f32_16x16x32_bf16(pa[0], *(const short8*)vp, accx[dt], 0, 0, 0);
      accx[dt] = __builtin_amdgcn_mfma_f32_16x16x32_bf16(pa[1], *(const short8*)(vp + 32), accx[dt], 0, 0, 0);
    }
  }

  // ---- per-row sum: reduce over the 16 lanes of each group, then across waves ----
#pragma unroll
  for (int off = 1; off < 16; off <<= 1) {
#pragma unroll
    for (int r = 0; r < 4; ++r) rsum[r] += __shfl_xor(rsum[r], off);
  }
  if (lm == 0) {
#pragma unroll
    for (int r = 0; r < 4; ++r) atomicAdd(&zrow[4 * g + r], rsum[r]);
  }
  // ---- PV partials into LDS ----
#pragma unroll
  for (int dt = 0; dt < 8; ++dt) {
#pragma unroll
    for (int r = 0; r < 4; ++r)
      atomicAdd(&xbuf[(4 * g + r) * D_DIM + dt * 16 + lm], accx[dt][r]);
  }
  __syncthreads();
  if (tid < 16) zrow[tid] = 1.0f / zrow[tid];
  __syncthreads();

  // ---- write normalized attention weights (fp32, coalesced, nontemporal) ----
  {
    float* wbase = out_w + (((size_t)n * L_DIM) + l0) * (size_t)S_DIM;
    for (int i = tid; i < 16 * (S_DIM / 4); i += 256) {
      const int r = i >> 9;
      const int c = (i & 511) << 2;
      const float iz = zrow[r];
      u16x4 pv = *(const u16x4*)&Pl[r * PSTRIDE + c];
      f32x4 o = { bf2f(pv[0]) * iz, bf2f(pv[1]) * iz, bf2f(pv[2]) * iz, bf2f(pv[3]) * iz };
      __builtin_nontemporal_store(o, (f32x4*)(wbase + (size_t)r * S_DIM + c));
    }
  }
  // ---- write x ----
  {
    float* xbase = out_x + (((size_t)n * L_DIM) + l0) * (size_t)D_DIM;
    for (int i = tid; i < 16 * (D_DIM / 4); i += 256) {
      const int r = i >> 5;
      const int c = (i & 31) << 2;
      const float iz = zrow[r];
      f32x4 o = { xbuf[r * D_DIM + c + 0] * iz, xbuf[r * D_DIM + c + 1] * iz,
                  xbuf[r * D_DIM + c + 2] * iz, xbuf[r * D_DIM + c + 3] * iz };
      __builtin_nontemporal_store(o, (f32x4*)(xbase + (size_t)r * D_DIM + c));
    }
  }
}

extern "C" void kernel_launch(void* const* d_in, const int* in_sizes, int n_in,
                              void* d_out, int out_size, void* d_ws, size_t ws_size,
                              hipStream_t stream) {
  const float* Q = (const float*)d_in[0];
  const float* K = (const float*)d_in[1];
  const float* V = (const float*)d_in[2];
  const void* mask = d_in[3];

  float* out_x = (float*)d_out;
  float* out_w = out_x + (size_t)N_B * L_DIM * D_DIM;

  unsigned short* Kb = (unsigned short*)d_ws;                       // 8 MB
  unsigned short* Vt = Kb + (size_t)N_B * S_DIM * D_DIM;            // 8 MB
  const size_t tail = (size_t)16 * 1024 * 1024;
  int* flag = (ws_size >= tail + 16) ? (int*)((char*)d_ws + tail) : nullptr;

  if (flag)
    detect_mask_kernel<<<dim3(1), dim3(256), 0, stream>>>((const unsigned int*)mask, flag);
  cvt_k_kernel<<<dim3(1024), dim3(256), 0, stream>>>(K, Kb);
  transpose_v_kernel<<<dim3(S_DIM / 64, D_DIM / 64, N_B), dim3(256), 0, stream>>>(V, Vt);
  attn_main<<<dim3(L_DIM / 16, N_B), dim3(256), 0, stream>>>(Q, mask, flag, Kb, Vt, out_x, out_w);
}